// Round 1
// 453.423 us; speedup vs baseline: 1.0568x; 1.0568x over previous
//
#include <hip/hip_runtime.h>
#include <cmath>

typedef __bf16 bf16x8 __attribute__((ext_vector_type(8)));
typedef float  f32x4  __attribute__((ext_vector_type(4)));

#define MFMA16(a,b,c) __builtin_amdgcn_mfma_f32_16x16x32_bf16((a),(b),(c),0,0,0)

// DIM=96 NH=3 HEAD=32 WS=7 SHIFT=3 P=5 H=W=56 NWH=NWW=8 NW=64 TP=320 N=54 HIDDEN=384 B=64
#define SCALE_Q 0.17677669529663687f   // 32^-0.5

// LDS strides (bf16 elems)
#define KST 104  // kt & scratch rows: 52 dw, l15*20 mod 32 -> 2-way (free)
#define VP  68   // vT / P rows: 34 dw, same pattern as previous kernel

// LDS map (39680 B total -> 4 blocks/CU):
//  kt  [0,13312)      [64][KST] bf16  k token-major        (P2 -> P3)
//  vT  [13312,26368)  [96][VP]  bf16  v feature-major      (P2 -> P5)
//  sw  [26368,39680)  4 x [16][KST] bf16 per-wave scratch  (wave-private, all phases)
//  obf [0,25600)      [64][100] f32   y accumulator        (P6 -> end, aliases kt+vT)

// ---------------- prep: weight convert (fp32 -> bf16 [n][k]) + bias/mask table ----------------
__global__ __launch_bounds__(256) void prep(const float* __restrict__ qkv_w,
                                            const float* __restrict__ proj_w,
                                            const float* __restrict__ fc1_w,
                                            const float* __restrict__ fc2_w,
                                            const float* __restrict__ rpb,
                                            __bf16* __restrict__ ws,
                                            float* __restrict__ tbl)
{
    int i = blockIdx.x * 256 + threadIdx.x;   // grid covers 110592 exactly
    {
        int j = i;
        if (j < 27648) {                       // qkv_w (96,288) -> [c][k], fold q-scale
            int c = j / 96, k = j % 96;
            float v = qkv_w[k * 288 + c];
            if (c < 96) v *= SCALE_Q;
            ws[j] = (__bf16)v;
        } else if ((j -= 27648) < 9216) {      // proj_w (96,96)
            int c = j / 96, k = j % 96;
            ws[27648 + j] = (__bf16)proj_w[k * 96 + c];
        } else if ((j -= 9216) < 36864) {      // fc1_w (96,384)
            int c = j / 96, k = j % 96;
            ws[36864 + j] = (__bf16)fc1_w[k * 384 + c];
        } else if ((j -= 36864) < 36864) {     // fc2_w (384,96)
            int c = j / 384, k = j % 384;
            ws[73728 + j] = (__bf16)fc2_w[k * 96 + c];
        }
    }
    if (i < 49152) {                           // [cls(2x2)][h(3)][n(64)][m(64)] fp32
        int m = i & 63, n = (i >> 6) & 63, h = (i >> 12) % 3, cls = i / 12288;
        float v;
        if (m >= 54) {
            v = -1e30f;
        } else {
            v = 0.f;
            if (n >= 5 && n < 54 && m >= 5) {
                int an = n - 5, am = m - 5;
                int iy = an / 7, ix = an % 7, jy = am / 7, jx = am % 7;
                v = rpb[((iy - jy + 6) * 13 + (ix - jx + 6)) * 3 + h];
                int whp = cls >> 1, wwp = cls & 1;
                int idn = (whp ? (iy < 4 ? 1 : 2) : 0) * 3 + (wwp ? (ix < 4 ? 1 : 2) : 0);
                int idm = (whp ? (jy < 4 ? 1 : 2) : 0) * 3 + (wwp ? (jx < 4 ? 1 : 2) : 0);
                if (idn != idm) v -= 100.f;
            }
        }
        tbl[i] = v;
    }
}

// token index in x for window token t of window (b, w=wh*8+ww); gather==scatter
__device__ __forceinline__ int src_index(int b, int w, int wh, int ww, int t)
{
    if (t < 5) return b * 3456 + w * 5 + t;
    int a = t - 5;
    int hi = wh * 7 + a / 7 + 3; if (hi >= 56) hi -= 56;
    int wi = ww * 7 + a % 7 + 3; if (wi >= 56) wi -= 56;
    return b * 3456 + 320 + hi * 56 + wi;
}

// ============ fully fused block. Wave wv owns token rows [wv*16, wv*16+16) end-to-end.
// LDS 39680 B -> 4 blocks/CU; only 2 __syncthreads per block.
__global__ __launch_bounds__(256, 4) void block_fused(const float* __restrict__ x,
                                                  const float* __restrict__ n1g, const float* __restrict__ n1b,
                                                  const float* __restrict__ qkvb, const float* __restrict__ tbl,
                                                  const float* __restrict__ projb,
                                                  const float* __restrict__ n2g, const float* __restrict__ n2b,
                                                  const float* __restrict__ fc1b, const float* __restrict__ fc2b,
                                                  const __bf16* __restrict__ wqkvT, const __bf16* __restrict__ wprojT,
                                                  const __bf16* __restrict__ w1T, const __bf16* __restrict__ w2T,
                                                  float* __restrict__ out)
{
    __shared__ __align__(16) char smem[39680];
    __bf16* kt  = (__bf16*)(smem);            // [64][KST]
    __bf16* vT  = (__bf16*)(smem + 13312);    // [96][VP]
    float*  obf = (float*)(smem);             // [64][100] f32, alias kt+vT (live after barrier 2)

    const int tid  = threadIdx.x;
    const int lane = tid & 63;
    const int wv   = tid >> 6;
    const int l15  = lane & 15;
    const int quad = lane >> 4;

    __bf16* sw = (__bf16*)(smem + 26368) + wv * (16 * KST);   // per-wave [16][KST]

    const int g  = blockIdx.x;
    const int b  = g >> 6;
    const int w  = g & 63;
    const int wh = w >> 3;
    const int ww = w & 7;

    const int trow = wv * 16 + l15;                      // this lane's token row
    const int tsrc = src_index(b, w, wh, ww, trow < 54 ? trow : 53);

    // P1: gather + LN1 straight into A-fragment registers (row=trow, cols ks*32+quad*8)
    bf16x8 xnfr[3];
    {
        float xv[24];
        if (trow < 54) {
            const float* xr = x + (size_t)tsrc * 96 + quad * 8;
            #pragma unroll
            for (int ks = 0; ks < 3; ks++) {
                float4 a0 = *(const float4*)(xr + ks * 32);
                float4 a1 = *(const float4*)(xr + ks * 32 + 4);
                float* p = xv + ks * 8;
                p[0]=a0.x; p[1]=a0.y; p[2]=a0.z; p[3]=a0.w;
                p[4]=a1.x; p[5]=a1.y; p[6]=a1.z; p[7]=a1.w;
            }
        } else {
            #pragma unroll
            for (int j = 0; j < 24; j++) xv[j] = 0.f;
        }
        float s = 0.f, sq = 0.f;
        #pragma unroll
        for (int j = 0; j < 24; j++) { s += xv[j]; sq += xv[j] * xv[j]; }
        // row spread across the 4 quads of lanes == l15 (mod 16): 2-step reduce
        s  += __shfl_xor(s, 16, 64);  sq += __shfl_xor(sq, 16, 64);
        s  += __shfl_xor(s, 32, 64);  sq += __shfl_xor(sq, 32, 64);
        float mean = s * (1.f / 96.f);
        float rstd = rsqrtf(sq * (1.f / 96.f) - mean * mean + 1e-5f);
        float keep = (trow < 54) ? 1.f : 0.f;            // zero pad rows exactly
        #pragma unroll
        for (int ks = 0; ks < 3; ks++) {
            const float* gp = n1g + ks * 32 + quad * 8;
            const float* bp = n1b + ks * 32 + quad * 8;
            float4 g0 = *(const float4*)(gp), g1 = *(const float4*)(gp + 4);
            float4 b0 = *(const float4*)(bp), b1 = *(const float4*)(bp + 4);
            float gg[8] = {g0.x,g0.y,g0.z,g0.w,g1.x,g1.y,g1.z,g1.w};
            float bb[8] = {b0.x,b0.y,b0.z,b0.w,b1.x,b1.y,b1.z,b1.w};
            #pragma unroll
            for (int j = 0; j < 8; j++)
                xnfr[ks][j] = (__bf16)(((xv[ks*8+j] - mean) * rstd * gg[j] + bb[j]) * keep);
        }
    }

    // P2: QKV for own 16 rows. q -> per-wave scratch (transpose), k -> kt, v -> vT.
    #pragma unroll
    for (int nt = 0; nt < 6; nt++) {                     // q tiles
        const __bf16* br = wqkvT + (size_t)(nt * 16 + l15) * 96 + quad * 8;
        f32x4 acc = {0.f, 0.f, 0.f, 0.f};
        #pragma unroll
        for (int ks = 0; ks < 3; ks++)
            acc = MFMA16(xnfr[ks], *(const bf16x8*)(br + ks * 32), acc);
        int col = nt * 16 + l15;
        float bias = qkvb[col] * SCALE_Q;
        #pragma unroll
        for (int r = 0; r < 4; r++)
            sw[(quad * 4 + r) * KST + col] = (__bf16)(acc[r] + bias);
    }
    bf16x8 aq[3];                                        // own-row q A-frags (in-wave RAW via lgkmcnt)
    #pragma unroll
    for (int h = 0; h < 3; h++)
        aq[h] = *(const bf16x8*)(sw + l15 * KST + h * 32 + quad * 8);
    #pragma unroll
    for (int nt = 6; nt < 18; nt++) {                    // k and v tiles
        const __bf16* br = wqkvT + (size_t)(nt * 16 + l15) * 96 + quad * 8;
        f32x4 acc = {0.f, 0.f, 0.f, 0.f};
        #pragma unroll
        for (int ks = 0; ks < 3; ks++)
            acc = MFMA16(xnfr[ks], *(const bf16x8*)(br + ks * 32), acc);
        int col = nt * 16 + l15;
        float bias = qkvb[col];
        if (nt < 12) {
            int kc = col - 96;
            #pragma unroll
            for (int r = 0; r < 4; r++)
                kt[(wv * 16 + quad * 4 + r) * KST + kc] = (__bf16)(acc[r] + bias);
        } else {
            int vc = col - 192;
            #pragma unroll
            for (int r = 0; r < 4; r++)
                vT[vc * VP + (wv * 16 + quad * 4 + r)] = (__bf16)(acc[r] + bias);
        }
    }
    __syncthreads();   // barrier 1: kt/vT staged cross-wave

    // P3+P4+P5 fused per head (no barriers: P rows are wave-private)
    const int cls = ((wh == 7) ? 2 : 0) + ((ww == 7) ? 1 : 0);
    const float* tbc = tbl + cls * 12288;
    f32x4 oacc[6];
    #pragma unroll
    for (int i = 0; i < 6; i++) oacc[i] = (f32x4){0.f, 0.f, 0.f, 0.f};

    #pragma unroll
    for (int h = 0; h < 3; h++) {
        // scores S[own n][m] + bias/mask table
        float schv[4][4];
        const float* tbh = tbc + h * 4096 + (wv * 16 + quad * 4) * 64 + l15;
        #pragma unroll
        for (int nt = 0; nt < 4; nt++) {
            bf16x8 bk = *(const bf16x8*)(kt + (nt * 16 + l15) * KST + h * 32 + quad * 8);
            f32x4 c = {0.f, 0.f, 0.f, 0.f};
            c = MFMA16(aq[h], bk, c);
            #pragma unroll
            for (int r = 0; r < 4; r++)
                schv[nt][r] = c[r] + tbh[r * 64 + nt * 16];
        }
        // softmax over m; P -> per-wave scratch [16][VP]
        #pragma unroll
        for (int r = 0; r < 4; r++) {
            float mx = fmaxf(fmaxf(schv[0][r], schv[1][r]), fmaxf(schv[2][r], schv[3][r]));
            #pragma unroll
            for (int d = 1; d < 16; d <<= 1) mx = fmaxf(mx, __shfl_xor(mx, d, 16));
            float e0 = __expf(schv[0][r] - mx), e1 = __expf(schv[1][r] - mx);
            float e2 = __expf(schv[2][r] - mx), e3 = __expf(schv[3][r] - mx);
            float sum = e0 + e1 + e2 + e3;
            #pragma unroll
            for (int d = 1; d < 16; d <<= 1) sum += __shfl_xor(sum, d, 16);
            float inv = 1.f / sum;
            __bf16* pr = sw + (quad * 4 + r) * VP + l15;
            pr[0]  = (__bf16)(e0 * inv);
            pr[16] = (__bf16)(e1 * inv);
            pr[32] = (__bf16)(e2 * inv);
            pr[48] = (__bf16)(e3 * inv);
        }
        // P A-frags (row=own token) and PV for out cols h*32 + dt*16
        bf16x8 pa0 = *(const bf16x8*)(sw + l15 * VP + quad * 8);
        bf16x8 pa1 = *(const bf16x8*)(sw + l15 * VP + 32 + quad * 8);
        #pragma unroll
        for (int dt = 0; dt < 2; dt++) {
            const __bf16* vr = vT + (h * 32 + dt * 16 + l15) * VP + quad * 8;
            f32x4 acc = oacc[h * 2 + dt];
            acc = MFMA16(pa0, *(const bf16x8*)(vr), acc);
            acc = MFMA16(pa1, *(const bf16x8*)(vr + 32), acc);
            oacc[h * 2 + dt] = acc;
        }
    }

    // attn-out C-layout -> A-frags via per-wave scratch (before barrier 2)
    #pragma unroll
    for (int i = 0; i < 6; i++) {
        int colb = i * 16 + l15;                 // i = h*2+dt -> global col h*32+dt*16+l15
        #pragma unroll
        for (int r = 0; r < 4; r++)
            sw[(quad * 4 + r) * KST + colb] = (__bf16)oacc[i][r];
    }
    bf16x8 ofr[3];
    #pragma unroll
    for (int ks = 0; ks < 3; ks++)
        ofr[ks] = *(const bf16x8*)(sw + l15 * KST + ks * 32 + quad * 8);

    __syncthreads();   // barrier 2: all kt/vT reads done; obf (alias) may be written. LAST barrier.

    // P6: proj -> obf fp32 [64][100], wave-private rows
    #pragma unroll
    for (int nt = 0; nt < 6; nt++) {
        const __bf16* br = wprojT + (size_t)(nt * 16 + l15) * 96 + quad * 8;
        f32x4 acc = {0.f, 0.f, 0.f, 0.f};
        #pragma unroll
        for (int ks = 0; ks < 3; ks++)
            acc = MFMA16(ofr[ks], *(const bf16x8*)(br + ks * 32), acc);
        int col = nt * 16 + l15;
        float pb = projb[col];
        #pragma unroll
        for (int r = 0; r < 4; r++)
            obf[(wv * 16 + quad * 4 + r) * 100 + col] = acc[r] + pb;
    }

    // M1: y = x + a (A-frag layout row=trow); LN2 via quad shuffles
    float yv[24];
    float s = 0.f, sq = 0.f;
    {
        const float* xr = x + (size_t)tsrc * 96 + quad * 8;
        #pragma unroll
        for (int ks = 0; ks < 3; ks++) {
            float4 xa = *(const float4*)(xr + ks * 32);
            float4 xb = *(const float4*)(xr + ks * 32 + 4);
            float* ap = obf + trow * 100 + ks * 32 + quad * 8;
            float* yp = yv + ks * 8;
            yp[0] = xa.x + ap[0]; yp[1] = xa.y + ap[1]; yp[2] = xa.z + ap[2]; yp[3] = xa.w + ap[3];
            yp[4] = xb.x + ap[4]; yp[5] = xb.y + ap[5]; yp[6] = xb.z + ap[6]; yp[7] = xb.w + ap[7];
            #pragma unroll
            for (int j = 0; j < 8; j++) { s += yp[j]; sq += yp[j] * yp[j]; }
            ap[0] = yp[0]; ap[1] = yp[1]; ap[2] = yp[2]; ap[3] = yp[3];
            ap[4] = yp[4]; ap[5] = yp[5]; ap[6] = yp[6]; ap[7] = yp[7];
        }
    }
    s  += __shfl_xor(s, 16, 64);  sq += __shfl_xor(sq, 16, 64);
    s  += __shfl_xor(s, 32, 64);  sq += __shfl_xor(sq, 32, 64);
    float mean = s * (1.f / 96.f);
    float rstd = rsqrtf(sq * (1.f / 96.f) - mean * mean + 1e-5f);

    bf16x8 afr[3];
    #pragma unroll
    for (int ks = 0; ks < 3; ks++) {
        float4 g0 = *(const float4*)(n2g + ks * 32 + quad * 8);
        float4 g1 = *(const float4*)(n2g + ks * 32 + quad * 8 + 4);
        float4 b0 = *(const float4*)(n2b + ks * 32 + quad * 8);
        float4 b1 = *(const float4*)(n2b + ks * 32 + quad * 8 + 4);
        float gg[8] = {g0.x,g0.y,g0.z,g0.w,g1.x,g1.y,g1.z,g1.w};
        float bb[8] = {b0.x,b0.y,b0.z,b0.w,b1.x,b1.y,b1.z,b1.w};
        #pragma unroll
        for (int j = 0; j < 8; j++)
            afr[ks][j] = (__bf16)((yv[ks*8+j] - mean) * rstd * gg[j] + bb[j]);
    }

    // M2: fc1 + fast GELU; h -> fc2 A-fragments via per-wave scratch roundtrip ([16][40])
    bf16x8 hfr[12];
    for (int np = 0; np < 12; np++) {
        #pragma unroll
        for (int u = 0; u < 2; u++) {
            int ntx = np * 2 + u;
            const __bf16* br = w1T + (size_t)(ntx * 16 + l15) * 96 + quad * 8;
            f32x4 acc = {0.f, 0.f, 0.f, 0.f};
            #pragma unroll
            for (int ks = 0; ks < 3; ks++)
                acc = MFMA16(afr[ks], *(const bf16x8*)(br + ks * 32), acc);
            float fb = fc1b[ntx * 16 + l15];
            #pragma unroll
            for (int r = 0; r < 4; r++) {
                float v  = acc[r] + fb;
                float u2 = -1.5957691216057308f * v * (1.f + 0.044715f * v * v);
                float t  = __expf(u2);
                float ge = v * __builtin_amdgcn_rcpf(1.f + t);
                sw[(quad * 4 + r) * 40 + u * 16 + l15] = (__bf16)ge;
            }
        }
        hfr[np] = *(const bf16x8*)(sw + l15 * 40 + quad * 8);
    }

    // M3: obf(=y) += h @ fc2_wT + fc2_b (wave-private rows)
    for (int nt = 0; nt < 6; nt++) {
        int col = nt * 16 + l15;
        const __bf16* br = w2T + (size_t)col * 384 + quad * 8;
        f32x4 acc = {0.f, 0.f, 0.f, 0.f};
        #pragma unroll
        for (int ks = 0; ks < 12; ks++)
            acc = MFMA16(hfr[ks], *(const bf16x8*)(br + ks * 32), acc);
        float fb = fc2b[col];
        #pragma unroll
        for (int r = 0; r < 4; r++)
            obf[(wv * 16 + quad * 4 + r) * 100 + col] += acc[r] + fb;
    }

    // M4: scatter final rows (full 384 B granules; wave-private rows -> no barrier)
    #pragma unroll
    for (int it = 0; it < 6; it++) {
        int i = it * 64 + lane;          // < 384
        int rr = i / 24, seg = i - rr * 24;
        int row = wv * 16 + rr;
        if (row < 54) {
            int src = src_index(b, w, wh, ww, row);
            const float* sp = obf + row * 100 + seg * 4;
            float4 v = make_float4(sp[0], sp[1], sp[2], sp[3]);
            *(float4*)(out + (size_t)src * 96 + seg * 4) = v;
        }
    }
}

extern "C" void kernel_launch(void* const* d_in, const int* in_sizes, int n_in,
                              void* d_out, int out_size, void* d_ws, size_t ws_size,
                              hipStream_t stream)
{
    const float* x      = (const float*)d_in[0];
    const float* n1g    = (const float*)d_in[1];
    const float* n1b    = (const float*)d_in[2];
    const float* qkv_w  = (const float*)d_in[3];
    const float* qkv_b  = (const float*)d_in[4];
    const float* rpb    = (const float*)d_in[5];
    const float* proj_w = (const float*)d_in[6];
    const float* proj_b = (const float*)d_in[7];
    const float* n2g    = (const float*)d_in[8];
    const float* n2b    = (const float*)d_in[9];
    const float* fc1_w  = (const float*)d_in[10];
    const float* fc1_b  = (const float*)d_in[11];
    const float* fc2_w  = (const float*)d_in[12];
    const float* fc2_b  = (const float*)d_in[13];

    __bf16* ws     = (__bf16*)d_ws;
    __bf16* wqkvT  = ws;            // [288][96]
    __bf16* wprojT = ws + 27648;    // [96][96]
    __bf16* w1T    = ws + 36864;    // [384][96]
    __bf16* w2T    = ws + 73728;    // [96][384]
    float*  tbl    = (float*)((char*)d_ws + 221184);   // [4][3][64][64] fp32, 196608 B

    float* out = (float*)d_out;

    hipLaunchKernelGGL(prep, dim3(432), dim3(256), 0, stream,
                       qkv_w, proj_w, fc1_w, fc2_w, rpb, ws, tbl);
    hipLaunchKernelGGL(block_fused, dim3(4096), dim3(256), 0, stream,
                       x, n1g, n1b, qkv_b, tbl, proj_b, n2g, n2b, fc1_b, fc2_b,
                       wqkvT, wprojT, w1T, w2T, out);
}

// Round 2
// 357.369 us; speedup vs baseline: 1.3408x; 1.2688x over previous
//
#include <hip/hip_runtime.h>
#include <cmath>

typedef __bf16 bf16x8 __attribute__((ext_vector_type(8)));
typedef float  f32x4  __attribute__((ext_vector_type(4)));

#define MFMA16(a,b,c) __builtin_amdgcn_mfma_f32_16x16x32_bf16((a),(b),(c),0,0,0)

// DIM=96 NH=3 HEAD=32 WS=7 SHIFT=3 P=5 H=W=56 NWH=NWW=8 NW=64 TP=320 N=54 HIDDEN=384 B=64
#define SCALE_Q 0.17677669529663687f   // 32^-0.5

// LDS strides (bf16 elems)
#define KST 104  // kt & scratch rows: 52 dw % 32 = 20 -> 2-way (free)
#define VP  68   // vT / P rows: 34 dw % 32 = 2 -> 2-way (free)

// LDS map (79360 B total -> 2 blocks/CU), one block = TWO windows (wx=0,1):
//  kt[wx]  = smem + wx*13312          [64][KST] bf16   (P2 -> P3)
//  vT[wx]  = smem + 26624 + wx*13056  [96][VP]  bf16   (P2 -> P5)
//  sw[wx]  = smem + 52736 + (wv*2+wx)*3328  per-wave [16][KST] scratch
//  obf[wx] = smem + wx*25600          [64][100] f32    (P6 -> end, aliases kt/vT)

// ---------------- prep: weight convert (fp32 -> bf16 [n][k]) + bias/mask table ----------------
// Table layout is TRANSPOSED vs round 1: [cls(2x2)][h(3)][m(64)][n(64)] so a lane's 4
// consecutive n-values (r=0..3) are one float4.
__global__ __launch_bounds__(256) void prep(const float* __restrict__ qkv_w,
                                            const float* __restrict__ proj_w,
                                            const float* __restrict__ fc1_w,
                                            const float* __restrict__ fc2_w,
                                            const float* __restrict__ rpb,
                                            __bf16* __restrict__ ws,
                                            float* __restrict__ tbl)
{
    int i = blockIdx.x * 256 + threadIdx.x;   // grid covers 110592 exactly
    {
        int j = i;
        if (j < 27648) {                       // qkv_w (96,288) -> [c][k], fold q-scale
            int c = j / 96, k = j % 96;
            float v = qkv_w[k * 288 + c];
            if (c < 96) v *= SCALE_Q;
            ws[j] = (__bf16)v;
        } else if ((j -= 27648) < 9216) {      // proj_w (96,96)
            int c = j / 96, k = j % 96;
            ws[27648 + j] = (__bf16)proj_w[k * 96 + c];
        } else if ((j -= 9216) < 36864) {      // fc1_w (96,384)
            int c = j / 96, k = j % 96;
            ws[36864 + j] = (__bf16)fc1_w[k * 384 + c];
        } else if ((j -= 36864) < 36864) {     // fc2_w (384,96)
            int c = j / 384, k = j % 384;
            ws[73728 + j] = (__bf16)fc2_w[k * 96 + c];
        }
    }
    if (i < 49152) {                           // [cls][h][m][n] fp32 (transposed)
        int n = i & 63, m = (i >> 6) & 63, h = (i >> 12) % 3, cls = i / 12288;
        float v;
        if (m >= 54) {
            v = -1e30f;
        } else {
            v = 0.f;
            if (n >= 5 && n < 54 && m >= 5) {
                int an = n - 5, am = m - 5;
                int iy = an / 7, ix = an % 7, jy = am / 7, jx = am % 7;
                v = rpb[((iy - jy + 6) * 13 + (ix - jx + 6)) * 3 + h];
                int whp = cls >> 1, wwp = cls & 1;
                int idn = (whp ? (iy < 4 ? 1 : 2) : 0) * 3 + (wwp ? (ix < 4 ? 1 : 2) : 0);
                int idm = (whp ? (jy < 4 ? 1 : 2) : 0) * 3 + (wwp ? (jx < 4 ? 1 : 2) : 0);
                if (idn != idm) v -= 100.f;
            }
        }
        tbl[i] = v;
    }
}

// token index in x for window token t of window (b, w=wh*8+ww); gather==scatter
__device__ __forceinline__ int src_index(int b, int w, int wh, int ww, int t)
{
    if (t < 5) return b * 3456 + w * 5 + t;
    int a = t - 5;
    int hi = wh * 7 + a / 7 + 3; if (hi >= 56) hi -= 56;
    int wi = ww * 7 + a % 7 + 3; if (wi >= 56) wi -= 56;
    return b * 3456 + 320 + hi * 56 + wi;
}

// ============ fully fused block, TWO windows per block (B-fragment reuse within each wave).
// Wave wv owns token rows [wv*16, wv*16+16) of both windows end-to-end. 2 __syncthreads.
__global__ __launch_bounds__(256, 2) void block_fused(const float* __restrict__ x,
                                                  const float* __restrict__ n1g, const float* __restrict__ n1b,
                                                  const float* __restrict__ qkvb, const float* __restrict__ tbl,
                                                  const float* __restrict__ projb,
                                                  const float* __restrict__ n2g, const float* __restrict__ n2b,
                                                  const float* __restrict__ fc1b, const float* __restrict__ fc2b,
                                                  const __bf16* __restrict__ wqkvT, const __bf16* __restrict__ wprojT,
                                                  const __bf16* __restrict__ w1T, const __bf16* __restrict__ w2T,
                                                  float* __restrict__ out)
{
    __shared__ __align__(16) char smem[79360];

    const int tid  = threadIdx.x;
    const int lane = tid & 63;
    const int wv   = tid >> 6;
    const int l15  = lane & 15;
    const int quad = lane >> 4;

    const int g  = blockIdx.x;          // 2048 blocks
    const int b  = g >> 5;
    const int wp = g & 31;              // window pair: windows 2*wp, 2*wp+1

    const int trow = wv * 16 + l15;     // this lane's token row

    __bf16* kt[2];  __bf16* vTp[2];  __bf16* sw[2];  float* obf[2];
    int wI[2], whI[2], wwI[2], clsI[2], tsrc[2];
    #pragma unroll
    for (int wx = 0; wx < 2; wx++) {
        kt[wx]  = (__bf16*)(smem + wx * 13312);
        vTp[wx] = (__bf16*)(smem + 26624 + wx * 13056);
        sw[wx]  = (__bf16*)(smem + 52736 + (wv * 2 + wx) * 3328);
        obf[wx] = (float*)(smem + wx * 25600);
        int w = wp * 2 + wx;
        wI[wx] = w;  whI[wx] = w >> 3;  wwI[wx] = w & 7;
        clsI[wx] = ((whI[wx] == 7) ? 2 : 0) + ((wwI[wx] == 7) ? 1 : 0);
        tsrc[wx] = src_index(b, w, whI[wx], wwI[wx], trow < 54 ? trow : 53);
    }

    // P1: gather + LN1 straight into A-fragment registers, both windows interleaved
    bf16x8 xnfr[2][3];
    {
        float xv[2][24];
        #pragma unroll
        for (int wx = 0; wx < 2; wx++) {
            if (trow < 54) {
                const float* xr = x + (size_t)tsrc[wx] * 96 + quad * 8;
                #pragma unroll
                for (int ks = 0; ks < 3; ks++) {
                    float4 a0 = *(const float4*)(xr + ks * 32);
                    float4 a1 = *(const float4*)(xr + ks * 32 + 4);
                    float* p = xv[wx] + ks * 8;
                    p[0]=a0.x; p[1]=a0.y; p[2]=a0.z; p[3]=a0.w;
                    p[4]=a1.x; p[5]=a1.y; p[6]=a1.z; p[7]=a1.w;
                }
            } else {
                #pragma unroll
                for (int j = 0; j < 24; j++) xv[wx][j] = 0.f;
            }
        }
        float s[2] = {0.f, 0.f}, sq[2] = {0.f, 0.f};
        #pragma unroll
        for (int wx = 0; wx < 2; wx++)
            #pragma unroll
            for (int j = 0; j < 24; j++) { s[wx] += xv[wx][j]; sq[wx] += xv[wx][j] * xv[wx][j]; }
        #pragma unroll
        for (int wx = 0; wx < 2; wx++) { s[wx] += __shfl_xor(s[wx], 16, 64); sq[wx] += __shfl_xor(sq[wx], 16, 64); }
        #pragma unroll
        for (int wx = 0; wx < 2; wx++) { s[wx] += __shfl_xor(s[wx], 32, 64); sq[wx] += __shfl_xor(sq[wx], 32, 64); }
        float mean[2], rstd[2];
        #pragma unroll
        for (int wx = 0; wx < 2; wx++) {
            mean[wx] = s[wx] * (1.f / 96.f);
            rstd[wx] = rsqrtf(sq[wx] * (1.f / 96.f) - mean[wx] * mean[wx] + 1e-5f);
        }
        float keep = (trow < 54) ? 1.f : 0.f;
        #pragma unroll
        for (int ks = 0; ks < 3; ks++) {
            const float* gp = n1g + ks * 32 + quad * 8;
            const float* bp = n1b + ks * 32 + quad * 8;
            float4 g0 = *(const float4*)(gp), g1 = *(const float4*)(gp + 4);
            float4 b0 = *(const float4*)(bp), b1 = *(const float4*)(bp + 4);
            float gg[8] = {g0.x,g0.y,g0.z,g0.w,g1.x,g1.y,g1.z,g1.w};
            float bb[8] = {b0.x,b0.y,b0.z,b0.w,b1.x,b1.y,b1.z,b1.w};
            #pragma unroll
            for (int wx = 0; wx < 2; wx++)
                #pragma unroll
                for (int j = 0; j < 8; j++)
                    xnfr[wx][ks][j] = (__bf16)(((xv[wx][ks*8+j] - mean[wx]) * rstd[wx] * gg[j] + bb[j]) * keep);
        }
    }

    // P2: QKV; each B-fragment loaded ONCE, used for both windows.
    #pragma unroll
    for (int nt = 0; nt < 6; nt++) {                     // q tiles -> per-wave scratch (transpose)
        const __bf16* br = wqkvT + (size_t)(nt * 16 + l15) * 96 + quad * 8;
        bf16x8 bf0 = *(const bf16x8*)(br);
        bf16x8 bf1 = *(const bf16x8*)(br + 32);
        bf16x8 bf2 = *(const bf16x8*)(br + 64);
        int col = nt * 16 + l15;
        float bias = qkvb[col] * SCALE_Q;
        #pragma unroll
        for (int wx = 0; wx < 2; wx++) {
            f32x4 acc = {0.f, 0.f, 0.f, 0.f};
            acc = MFMA16(xnfr[wx][0], bf0, acc);
            acc = MFMA16(xnfr[wx][1], bf1, acc);
            acc = MFMA16(xnfr[wx][2], bf2, acc);
            #pragma unroll
            for (int r = 0; r < 4; r++)
                sw[wx][(quad * 4 + r) * KST + col] = (__bf16)(acc[r] + bias);
        }
    }
    bf16x8 aq[2][3];                                     // own-row q A-frags (in-wave RAW via lgkmcnt)
    #pragma unroll
    for (int wx = 0; wx < 2; wx++)
        #pragma unroll
        for (int h = 0; h < 3; h++)
            aq[wx][h] = *(const bf16x8*)(sw[wx] + l15 * KST + h * 32 + quad * 8);
    #pragma unroll
    for (int nt = 6; nt < 18; nt++) {                    // k and v tiles
        const __bf16* br = wqkvT + (size_t)(nt * 16 + l15) * 96 + quad * 8;
        bf16x8 bf0 = *(const bf16x8*)(br);
        bf16x8 bf1 = *(const bf16x8*)(br + 32);
        bf16x8 bf2 = *(const bf16x8*)(br + 64);
        int col = nt * 16 + l15;
        float bias = qkvb[col];
        #pragma unroll
        for (int wx = 0; wx < 2; wx++) {
            f32x4 acc = {0.f, 0.f, 0.f, 0.f};
            acc = MFMA16(xnfr[wx][0], bf0, acc);
            acc = MFMA16(xnfr[wx][1], bf1, acc);
            acc = MFMA16(xnfr[wx][2], bf2, acc);
            if (nt < 12) {
                int kc = col - 96;
                #pragma unroll
                for (int r = 0; r < 4; r++)
                    kt[wx][(wv * 16 + quad * 4 + r) * KST + kc] = (__bf16)(acc[r] + bias);
            } else {
                int vc = col - 192;
                #pragma unroll
                for (int r = 0; r < 4; r++)
                    vTp[wx][vc * VP + (wv * 16 + quad * 4 + r)] = (__bf16)(acc[r] + bias);
            }
        }
    }
    __syncthreads();   // barrier 1: kt/vT staged cross-wave

    // P3+P4+P5 fused per head, both windows interleaved (P rows are wave-private scratch)
    f32x4 oacc[2][6];
    #pragma unroll
    for (int wx = 0; wx < 2; wx++)
        #pragma unroll
        for (int i = 0; i < 6; i++) oacc[wx][i] = (f32x4){0.f, 0.f, 0.f, 0.f};

    #pragma unroll
    for (int h = 0; h < 3; h++) {
        float schv[2][4][4];
        #pragma unroll
        for (int wx = 0; wx < 2; wx++) {
            const float* tbT = tbl + (size_t)(clsI[wx] * 3 + h) * 4096;
            #pragma unroll
            for (int nt = 0; nt < 4; nt++) {
                bf16x8 bk = *(const bf16x8*)(kt[wx] + (nt * 16 + l15) * KST + h * 32 + quad * 8);
                f32x4 c = {0.f, 0.f, 0.f, 0.f};
                c = MFMA16(aq[wx][h], bk, c);
                float4 tv = *(const float4*)(tbT + (l15 + 16 * nt) * 64 + wv * 16 + quad * 4);
                schv[wx][nt][0] = c[0] + tv.x;
                schv[wx][nt][1] = c[1] + tv.y;
                schv[wx][nt][2] = c[2] + tv.z;
                schv[wx][nt][3] = c[3] + tv.w;
            }
        }
        // softmax over m, both windows interleaved; P -> per-wave scratch [16][VP]
        #pragma unroll
        for (int r = 0; r < 4; r++) {
            float mx[2], e0[2], e1[2], e2[2], e3[2], sum[2];
            #pragma unroll
            for (int wx = 0; wx < 2; wx++)
                mx[wx] = fmaxf(fmaxf(schv[wx][0][r], schv[wx][1][r]), fmaxf(schv[wx][2][r], schv[wx][3][r]));
            #pragma unroll
            for (int d = 1; d < 16; d <<= 1)
                #pragma unroll
                for (int wx = 0; wx < 2; wx++) mx[wx] = fmaxf(mx[wx], __shfl_xor(mx[wx], d, 16));
            #pragma unroll
            for (int wx = 0; wx < 2; wx++) {
                e0[wx] = __expf(schv[wx][0][r] - mx[wx]);
                e1[wx] = __expf(schv[wx][1][r] - mx[wx]);
                e2[wx] = __expf(schv[wx][2][r] - mx[wx]);
                e3[wx] = __expf(schv[wx][3][r] - mx[wx]);
                sum[wx] = e0[wx] + e1[wx] + e2[wx] + e3[wx];
            }
            #pragma unroll
            for (int d = 1; d < 16; d <<= 1)
                #pragma unroll
                for (int wx = 0; wx < 2; wx++) sum[wx] += __shfl_xor(sum[wx], d, 16);
            #pragma unroll
            for (int wx = 0; wx < 2; wx++) {
                float inv = 1.f / sum[wx];
                __bf16* prw = sw[wx] + (quad * 4 + r) * VP + l15;
                prw[0]  = (__bf16)(e0[wx] * inv);
                prw[16] = (__bf16)(e1[wx] * inv);
                prw[32] = (__bf16)(e2[wx] * inv);
                prw[48] = (__bf16)(e3[wx] * inv);
            }
        }
        // P A-frags and PV, both windows
        bf16x8 pa0[2], pa1[2];
        #pragma unroll
        for (int wx = 0; wx < 2; wx++) {
            pa0[wx] = *(const bf16x8*)(sw[wx] + l15 * VP + quad * 8);
            pa1[wx] = *(const bf16x8*)(sw[wx] + l15 * VP + 32 + quad * 8);
        }
        #pragma unroll
        for (int wx = 0; wx < 2; wx++)
            #pragma unroll
            for (int dt = 0; dt < 2; dt++) {
                const __bf16* vr = vTp[wx] + (h * 32 + dt * 16 + l15) * VP + quad * 8;
                f32x4 acc = oacc[wx][h * 2 + dt];
                acc = MFMA16(pa0[wx], *(const bf16x8*)(vr), acc);
                acc = MFMA16(pa1[wx], *(const bf16x8*)(vr + 32), acc);
                oacc[wx][h * 2 + dt] = acc;
            }
    }

    // attn-out C-layout -> A-frags via per-wave scratch (before barrier 2)
    #pragma unroll
    for (int wx = 0; wx < 2; wx++)
        #pragma unroll
        for (int i = 0; i < 6; i++) {
            int colb = i * 16 + l15;
            #pragma unroll
            for (int r = 0; r < 4; r++)
                sw[wx][(quad * 4 + r) * KST + colb] = (__bf16)oacc[wx][i][r];
        }
    bf16x8 ofr[2][3];
    #pragma unroll
    for (int wx = 0; wx < 2; wx++)
        #pragma unroll
        for (int ks = 0; ks < 3; ks++)
            ofr[wx][ks] = *(const bf16x8*)(sw[wx] + l15 * KST + ks * 32 + quad * 8);

    __syncthreads();   // barrier 2: all kt/vT reads done; obf (alias) may be written. LAST barrier.

    // P6: proj -> obf fp32 [64][100], wave-private rows; shared B-fragments
    #pragma unroll
    for (int nt = 0; nt < 6; nt++) {
        const __bf16* br = wprojT + (size_t)(nt * 16 + l15) * 96 + quad * 8;
        bf16x8 bf0 = *(const bf16x8*)(br);
        bf16x8 bf1 = *(const bf16x8*)(br + 32);
        bf16x8 bf2 = *(const bf16x8*)(br + 64);
        int col = nt * 16 + l15;
        float pb = projb[col];
        #pragma unroll
        for (int wx = 0; wx < 2; wx++) {
            f32x4 acc = {0.f, 0.f, 0.f, 0.f};
            acc = MFMA16(ofr[wx][0], bf0, acc);
            acc = MFMA16(ofr[wx][1], bf1, acc);
            acc = MFMA16(ofr[wx][2], bf2, acc);
            #pragma unroll
            for (int r = 0; r < 4; r++)
                obf[wx][(wv * 16 + quad * 4 + r) * 100 + col] = acc[r] + pb;
        }
    }

    // M1: y = x + a; LN2, both windows interleaved
    float yv[2][24];
    float s2[2] = {0.f, 0.f}, sq2[2] = {0.f, 0.f};
    #pragma unroll
    for (int wx = 0; wx < 2; wx++) {
        const float* xr = x + (size_t)tsrc[wx] * 96 + quad * 8;
        #pragma unroll
        for (int ks = 0; ks < 3; ks++) {
            float4 xa = *(const float4*)(xr + ks * 32);
            float4 xb = *(const float4*)(xr + ks * 32 + 4);
            float* ap = obf[wx] + trow * 100 + ks * 32 + quad * 8;
            float* yp = yv[wx] + ks * 8;
            yp[0] = xa.x + ap[0]; yp[1] = xa.y + ap[1]; yp[2] = xa.z + ap[2]; yp[3] = xa.w + ap[3];
            yp[4] = xb.x + ap[4]; yp[5] = xb.y + ap[5]; yp[6] = xb.z + ap[6]; yp[7] = xb.w + ap[7];
            #pragma unroll
            for (int j = 0; j < 8; j++) { s2[wx] += yp[j]; sq2[wx] += yp[j] * yp[j]; }
            ap[0] = yp[0]; ap[1] = yp[1]; ap[2] = yp[2]; ap[3] = yp[3];
            ap[4] = yp[4]; ap[5] = yp[5]; ap[6] = yp[6]; ap[7] = yp[7];
        }
    }
    #pragma unroll
    for (int wx = 0; wx < 2; wx++) { s2[wx] += __shfl_xor(s2[wx], 16, 64); sq2[wx] += __shfl_xor(sq2[wx], 16, 64); }
    #pragma unroll
    for (int wx = 0; wx < 2; wx++) { s2[wx] += __shfl_xor(s2[wx], 32, 64); sq2[wx] += __shfl_xor(sq2[wx], 32, 64); }
    float mean2[2], rstd2[2];
    #pragma unroll
    for (int wx = 0; wx < 2; wx++) {
        mean2[wx] = s2[wx] * (1.f / 96.f);
        rstd2[wx] = rsqrtf(sq2[wx] * (1.f / 96.f) - mean2[wx] * mean2[wx] + 1e-5f);
    }

    bf16x8 afr[2][3];
    #pragma unroll
    for (int ks = 0; ks < 3; ks++) {
        float4 g0 = *(const float4*)(n2g + ks * 32 + quad * 8);
        float4 g1 = *(const float4*)(n2g + ks * 32 + quad * 8 + 4);
        float4 b0 = *(const float4*)(n2b + ks * 32 + quad * 8);
        float4 b1 = *(const float4*)(n2b + ks * 32 + quad * 8 + 4);
        float gg[8] = {g0.x,g0.y,g0.z,g0.w,g1.x,g1.y,g1.z,g1.w};
        float bb[8] = {b0.x,b0.y,b0.z,b0.w,b1.x,b1.y,b1.z,b1.w};
        #pragma unroll
        for (int wx = 0; wx < 2; wx++)
            #pragma unroll
            for (int j = 0; j < 8; j++)
                afr[wx][ks][j] = (__bf16)((yv[wx][ks*8+j] - mean2[wx]) * rstd2[wx] * gg[j] + bb[j]);
    }

    // M2: fc1 + fast GELU; shared B-fragments; h -> fc2 A-frags via scratch roundtrip ([16][40])
    bf16x8 hfr[2][12];
    #pragma unroll
    for (int np = 0; np < 12; np++) {
        #pragma unroll
        for (int u = 0; u < 2; u++) {
            int ntx = np * 2 + u;
            const __bf16* br = w1T + (size_t)(ntx * 16 + l15) * 96 + quad * 8;
            bf16x8 bf0 = *(const bf16x8*)(br);
            bf16x8 bf1 = *(const bf16x8*)(br + 32);
            bf16x8 bf2 = *(const bf16x8*)(br + 64);
            float fb = fc1b[ntx * 16 + l15];
            #pragma unroll
            for (int wx = 0; wx < 2; wx++) {
                f32x4 acc = {0.f, 0.f, 0.f, 0.f};
                acc = MFMA16(afr[wx][0], bf0, acc);
                acc = MFMA16(afr[wx][1], bf1, acc);
                acc = MFMA16(afr[wx][2], bf2, acc);
                #pragma unroll
                for (int r = 0; r < 4; r++) {
                    float v  = acc[r] + fb;
                    float u2 = -1.5957691216057308f * v * (1.f + 0.044715f * v * v);
                    float t  = __expf(u2);
                    float ge = v * __builtin_amdgcn_rcpf(1.f + t);
                    sw[wx][(quad * 4 + r) * 40 + u * 16 + l15] = (__bf16)ge;
                }
            }
        }
        #pragma unroll
        for (int wx = 0; wx < 2; wx++)
            hfr[wx][np] = *(const bf16x8*)(sw[wx] + l15 * 40 + quad * 8);
    }

    // M3: obf(=y) += h @ fc2_wT + fc2_b (wave-private rows); shared B-fragments
    #pragma unroll
    for (int nt = 0; nt < 6; nt++) {
        int col = nt * 16 + l15;
        const __bf16* br = w2T + (size_t)col * 384 + quad * 8;
        float fb = fc2b[col];
        f32x4 acc0 = {0.f, 0.f, 0.f, 0.f};
        f32x4 acc1 = {0.f, 0.f, 0.f, 0.f};
        #pragma unroll
        for (int ks = 0; ks < 12; ks++) {
            bf16x8 bb = *(const bf16x8*)(br + ks * 32);
            acc0 = MFMA16(hfr[0][ks], bb, acc0);
            acc1 = MFMA16(hfr[1][ks], bb, acc1);
        }
        #pragma unroll
        for (int r = 0; r < 4; r++) {
            obf[0][(wv * 16 + quad * 4 + r) * 100 + col] += acc0[r] + fb;
            obf[1][(wv * 16 + quad * 4 + r) * 100 + col] += acc1[r] + fb;
        }
    }

    // M4: scatter final rows (wave-private rows -> no barrier)
    #pragma unroll
    for (int wx = 0; wx < 2; wx++)
        #pragma unroll
        for (int it = 0; it < 6; it++) {
            int i = it * 64 + lane;          // < 384
            int rr = i / 24, seg = i - rr * 24;
            int row = wv * 16 + rr;
            if (row < 54) {
                int src = src_index(b, wI[wx], whI[wx], wwI[wx], row);
                const float* sp = obf[wx] + row * 100 + seg * 4;
                float4 v = make_float4(sp[0], sp[1], sp[2], sp[3]);
                *(float4*)(out + (size_t)src * 96 + seg * 4) = v;
            }
        }
}

extern "C" void kernel_launch(void* const* d_in, const int* in_sizes, int n_in,
                              void* d_out, int out_size, void* d_ws, size_t ws_size,
                              hipStream_t stream)
{
    const float* x      = (const float*)d_in[0];
    const float* n1g    = (const float*)d_in[1];
    const float* n1b    = (const float*)d_in[2];
    const float* qkv_w  = (const float*)d_in[3];
    const float* qkv_b  = (const float*)d_in[4];
    const float* rpb    = (const float*)d_in[5];
    const float* proj_w = (const float*)d_in[6];
    const float* proj_b = (const float*)d_in[7];
    const float* n2g    = (const float*)d_in[8];
    const float* n2b    = (const float*)d_in[9];
    const float* fc1_w  = (const float*)d_in[10];
    const float* fc1_b  = (const float*)d_in[11];
    const float* fc2_w  = (const float*)d_in[12];
    const float* fc2_b  = (const float*)d_in[13];

    __bf16* ws     = (__bf16*)d_ws;
    __bf16* wqkvT  = ws;            // [288][96]
    __bf16* wprojT = ws + 27648;    // [96][96]
    __bf16* w1T    = ws + 36864;    // [384][96]
    __bf16* w2T    = ws + 73728;    // [96][384]
    float*  tbl    = (float*)((char*)d_ws + 221184);   // [4][3][64][64] fp32, 196608 B

    float* out = (float*)d_out;

    hipLaunchKernelGGL(prep, dim3(432), dim3(256), 0, stream,
                       qkv_w, proj_w, fc1_w, fc2_w, rpb, ws, tbl);
    hipLaunchKernelGGL(block_fused, dim3(2048), dim3(256), 0, stream,
                       x, n1g, n1b, qkv_b, tbl, proj_b, n2g, n2b, fc1_b, fc2_b,
                       wqkvT, wprojT, w1T, w2T, out);
}